// Round 7
// baseline (640.503 us; speedup 1.0000x reference)
//
#include <hip/hip_runtime.h>

typedef short s8v  __attribute__((ext_vector_type(8)));
typedef float f4v  __attribute__((ext_vector_type(4)));
typedef int   v4i  __attribute__((ext_vector_type(4)));
typedef float v4f  __attribute__((ext_vector_type(4)));

#define NNODES 8192
#define FDIM   256
#define NJC    4          // j-chunks (split-K factor)
#define JLEN   2048       // columns-j per chunk
#define TROWS  16         // rows per block
#define NSTEP  16         // JLEN / 128

__device__ __forceinline__ float bf2f(unsigned short u) {
    unsigned int x = ((unsigned int)u) << 16;
    return __builtin_bit_cast(float, x);
}
__device__ __forceinline__ unsigned short f2bf(float f) {
    unsigned int x = __builtin_bit_cast(unsigned int, f);
    x += 0x7fffu + ((x >> 16) & 1u);
    return (unsigned short)(x >> 16);
}

// ---------------- Kernel 0: WT[n][k] = bf16(W[k][n]) ----------------
__global__ __launch_bounds__(256) void wt_kernel(const float* __restrict__ W,
                                                 unsigned short* __restrict__ WT) {
    int idx = blockIdx.x * 256 + threadIdx.x;
    int r = idx >> 8, c = idx & 255;
    WT[c * 256 + r] = f2bf(W[r * 256 + c]);
}

// ---------------- Kernel 0b: v1 = W @ a[:256], v2 = W @ a[256:] ----------------
__global__ __launch_bounds__(256) void wv_kernel(const float* __restrict__ W,
                                                 const float* __restrict__ a,
                                                 float* __restrict__ v1, float* __restrict__ v2) {
    __shared__ float r1[256], r2[256];
    int b = blockIdx.x, n = threadIdx.x;
    float w = W[(size_t)b * FDIM + n];
    r1[n] = w * a[n];
    r2[n] = w * a[FDIM + n];
    __syncthreads();
    for (int off = 128; off > 0; off >>= 1) {
        if (n < off) { r1[n] += r1[n + off]; r2[n] += r2[n + off]; }
        __syncthreads();
    }
    if (n == 0) { v1[b] = r1[0]; v2[b] = r2[0]; }
}

// ---------------- Kernel 0c: pack adj -> bitmask in attn layout ----------------
// PM byte address row*1024 + jc*256 + idx*16 + s; bit jj of that byte =
// (adj[row][jc*2048 + s*128 + idx*8 + jj] > 0). One block per row; pure
// streaming (no cross-iteration deps) so it runs at HBM BW unlike the
// latency-chained per-step adj loads it replaces.
__global__ __launch_bounds__(256) void pack_kernel(const int* __restrict__ adj,
                                                   unsigned char* __restrict__ PM) {
    __shared__ unsigned char lin[1024];   // linear byte b = adj bits [b*8, b*8+8)
    int row = blockIdx.x, t = threadIdx.x;
    const v4i* src = (const v4i*)(adj + (size_t)row * NNODES);

    // thread t: 32 ints (j = t*32..+31) -> 4 linear bytes at lin[4t..4t+3]
    unsigned int bytes = 0;
#pragma unroll
    for (int b = 0; b < 4; ++b) {
        unsigned int m = 0;
#pragma unroll
        for (int v = 0; v < 2; ++v) {
            v4i x = src[t * 8 + b * 2 + v];
#pragma unroll
            for (int j = 0; j < 4; ++j)
                if (x[j] > 0) m |= 1u << (v * 4 + j);
        }
        bytes |= m << (b * 8);
    }
    *(unsigned int*)&lin[t * 4] = bytes;
    __syncthreads();

    // gather into PM order; write is perfectly linear: dst byte = row*1024 + 4t
    int jc = t >> 6, idx = (t >> 2) & 15, sq = (t & 3) * 4;
    unsigned int ob = 0;
#pragma unroll
    for (int k = 0; k < 4; ++k)
        ob |= (unsigned int)lin[jc * 256 + (sq + k) * 16 + idx] << (k * 8);
    *(unsigned int*)&PM[(size_t)row * 1024 + t * 4] = ob;
}

// ---------------- Kernel 1: WhT = bf16((h@W)^T); s1/s2 = h@v (fp32) ----------------
__global__ __launch_bounds__(256) void wh_kernel(
    const float* __restrict__ h, const unsigned short* __restrict__ WT,
    const float* __restrict__ v1, const float* __restrict__ v2,
    unsigned short* __restrict__ WhT,
    float* __restrict__ s1, float* __restrict__ s2)
{
    __shared__ float v1_lds[FDIM], v2_lds[FDIM];
    int tid = threadIdx.x;
    v1_lds[tid] = v1[tid];
    v2_lds[tid] = v2[tid];
    __syncthreads();

    int w = tid >> 6, lane = tid & 63, q = lane >> 4, l15 = lane & 15;
    int i_base = blockIdx.x * 64 + w * 16;

    f4v acc[16] = {};
    float s1p = 0.f, s2p = 0.f;

    for (int k0 = 0; k0 < 256; k0 += 32) {
        const float* hp = h + (size_t)(i_base + l15) * FDIM + k0 + q * 8;
        f4v h0 = *(const f4v*)hp;
        f4v h1 = *(const f4v*)(hp + 4);
        s8v af;
#pragma unroll
        for (int j = 0; j < 4; ++j) {
            af[j]     = (short)f2bf(h0[j]);
            af[4 + j] = (short)f2bf(h1[j]);
            s1p += h0[j] * v1_lds[k0 + q * 8 + j] + h1[j] * v1_lds[k0 + q * 8 + 4 + j];
            s2p += h0[j] * v2_lds[k0 + q * 8 + j] + h1[j] * v2_lds[k0 + q * 8 + 4 + j];
        }
#pragma unroll
        for (int t = 0; t < 16; ++t) {
            s8v bf = *(const s8v*)(WT + (size_t)(t * 16 + l15) * FDIM + k0 + q * 8);
            acc[t] = __builtin_amdgcn_mfma_f32_16x16x32_bf16(af, bf, acc[t], 0, 0, 0);
        }
    }

    s1p += __shfl_xor(s1p, 16, 64);
    s1p += __shfl_xor(s1p, 32, 64);
    s2p += __shfl_xor(s2p, 16, 64);
    s2p += __shfl_xor(s2p, 32, 64);
    if (lane < 16) {
        s1[i_base + lane] = s1p;
        s2[i_base + lane] = s2p;
    }

#pragma unroll
    for (int t = 0; t < 16; ++t)
#pragma unroll
        for (int r = 0; r < 4; ++r)
            WhT[(size_t)(t * 16 + l15) * NNODES + i_base + q * 4 + r] = f2bf(acc[t][r]);
}

// ---------------- Kernel 2: split-K partial attention (mask-fed) ----------------
// grid 2048 = 512 row-tiles x 4 j-chunks, 256 threads. 16 steps of k=128.
// The K-loop has NO adj traffic: each P-gen thread preloads its 16-step mask
// (16 B) once. Only per-step vmem = L2/L3-resident WhT B-frags.
__global__ __launch_bounds__(256) void attn_partial(
    const unsigned char* __restrict__ PM, const unsigned short* __restrict__ WhT,
    const float* __restrict__ s1, const float* __restrict__ s2,
    float* __restrict__ Npart, float* __restrict__ dpart)
{
    __shared__ float s2_lds[JLEN];                    // 8 KB slice
    __shared__ unsigned short P_lds[2][TROWS * 128];  // 2 x 4 KB, swizzled
    __shared__ float dsum_lds[TROWS][16];

    int tid = threadIdx.x;
    int rt = blockIdx.x & 511, jc = blockIdx.x >> 9;
    int j0 = jc * JLEN;

    // stage s2 slice
    for (int i = tid; i < JLEN / 4; i += 256)
        ((v4f*)s2_lds)[i] = ((const v4f*)(s2 + j0))[i];

    // P-generator role
    int m = tid >> 4, idx = tid & 15;
    int row_g = rt * TROWS + m;
    float s1v = s1[row_g];
    // preload all 16 steps' mask bytes (byte s: bits jj for j = j0+s*128+idx*8+jj)
    ulonglong2 ml = *(const ulonglong2*)(PM + (size_t)row_g * 1024 + jc * 256 + idx * 16);
    unsigned long long mlo = ml.x, mhi = ml.y;
    // write slot = idx*16+m; swizzled: slot*8 ^ ((idx&1)*32) (2-way, free)
    int woff = ((idx * 16 + m) * 8) ^ ((idx & 1) * 32);

    // MFMA role: wave g handles cols g*64 + t*16 + l15
    int g = tid >> 6, lane = tid & 63, q = lane >> 4, l15 = lane & 15;
    const unsigned short* bb[4];
#pragma unroll
    for (int t = 0; t < 4; ++t)
        bb[t] = WhT + (size_t)(g * 64 + t * 16 + l15) * NNODES + j0 + q * 8;

    f4v acc[4] = {};
    float dsum = 0.0f;

    // barrier after s2 staging (R5 race fix)
    __syncthreads();

    // prologue: gen P for step 0 from mask byte 0
    {
        unsigned int mb = (unsigned int)(mlo & 0xffull);
        mlo = (mlo >> 8) | (mhi << 56); mhi >>= 8;
        int kb = idx * 8;
        v4f sA = *(const v4f*)&s2_lds[kb];
        v4f sB = *(const v4f*)&s2_lds[kb + 4];
        s8v pv;
#pragma unroll
        for (int j = 0; j < 4; ++j) {
            float x = s1v + sA[j];
            float p = ((mb >> j) & 1u) ? __expf(fmaxf(x, 0.2f * x)) : 0.0f;
            unsigned short pb = f2bf(p);
            pv[j] = (short)pb; dsum += bf2f(pb);
            float x2 = s1v + sB[j];
            float p2 = ((mb >> (4 + j)) & 1u) ? __expf(fmaxf(x2, 0.2f * x2)) : 0.0f;
            unsigned short pb2 = f2bf(p2);
            pv[4 + j] = (short)pb2; dsum += bf2f(pb2);
        }
        *(s8v*)&P_lds[0][woff] = pv;
    }
    __syncthreads();

    for (int s = 0; s < NSTEP; ++s) {
        int k0 = s * 128;

        // B-frags for step s (L2/L3-resident WhT)
        s8v bf[4][4];
#pragma unroll
        for (int c = 0; c < 4; ++c)
#pragma unroll
            for (int t = 0; t < 4; ++t)
                bf[c][t] = *(const s8v*)(bb[t] + k0 + c * 32);

        // P for step s+1 from preloaded mask byte
        if (s < NSTEP - 1) {
            unsigned int mb = (unsigned int)(mlo & 0xffull);
            mlo = (mlo >> 8) | (mhi << 56); mhi >>= 8;
            int kb = k0 + 128 + idx * 8;
            v4f sA = *(const v4f*)&s2_lds[kb];
            v4f sB = *(const v4f*)&s2_lds[kb + 4];
            s8v pv;
#pragma unroll
            for (int j = 0; j < 4; ++j) {
                float x = s1v + sA[j];
                float p = ((mb >> j) & 1u) ? __expf(fmaxf(x, 0.2f * x)) : 0.0f;
                unsigned short pb = f2bf(p);
                pv[j] = (short)pb; dsum += bf2f(pb);
                float x2 = s1v + sB[j];
                float p2 = ((mb >> (4 + j)) & 1u) ? __expf(fmaxf(x2, 0.2f * x2)) : 0.0f;
                unsigned short pb2 = f2bf(p2);
                pv[4 + j] = (short)pb2; dsum += bf2f(pb2);
            }
            *(s8v*)&P_lds[(s + 1) & 1][woff] = pv;
        }

        // A-frags: slot = (c*4+q)*16 + l15, swizzle ^(((c*4+q)&1)*32)
        const unsigned short* pbuf = P_lds[s & 1];
        s8v af[4];
#pragma unroll
        for (int c = 0; c < 4; ++c) {
            int ks = c * 4 + q;
            af[c] = *(const s8v*)&pbuf[((ks * 16 + l15) * 8) ^ ((ks & 1) * 32)];
        }

#pragma unroll
        for (int c = 0; c < 4; ++c)
#pragma unroll
            for (int t = 0; t < 4; ++t)
                acc[t] = __builtin_amdgcn_mfma_f32_16x16x32_bf16(af[c], bf[c][t], acc[t], 0, 0, 0);

        __syncthreads();
    }

    // partial denominator
    dsum_lds[m][idx] = dsum;
    __syncthreads();
    if (tid < TROWS) {
        float d = 0.f;
#pragma unroll
        for (int j = 0; j < 16; ++j) d += dsum_lds[tid][j];
        dpart[jc * NNODES + rt * TROWS + tid] = d;
    }

    // partial numerator: row = q*4+r, col = g*64 + t*16 + l15
#pragma unroll
    for (int r = 0; r < 4; ++r) {
        int row = q * 4 + r;
        float* base = Npart + ((size_t)(jc * NNODES) + rt * TROWS + row) * FDIM;
#pragma unroll
        for (int t = 0; t < 4; ++t)
            __builtin_nontemporal_store(acc[t][r], base + g * 64 + t * 16 + l15);
    }
}

// ---------------- Kernel 3: reduce partials, normalize ----------------
__global__ __launch_bounds__(256) void reduce_kernel(
    const float* __restrict__ Npart, const float* __restrict__ dpart,
    float* __restrict__ out)
{
    int i = blockIdx.x, n = threadIdx.x;
    float d = 0.f, acc = 0.f;
#pragma unroll
    for (int jc = 0; jc < NJC; ++jc) {
        d += dpart[jc * NNODES + i];
        acc += Npart[((size_t)(jc * NNODES) + i) * FDIM + n];
    }
    out[(size_t)i * FDIM + n] = acc / fmaxf(d, 1e-30f);
}

extern "C" void kernel_launch(void* const* d_in, const int* in_sizes, int n_in,
                              void* d_out, int out_size, void* d_ws, size_t ws_size,
                              hipStream_t stream) {
    const float* h   = (const float*)d_in[0];
    const int*   adj = (const int*)d_in[1];
    const float* W   = (const float*)d_in[2];
    const float* a   = (const float*)d_in[3];
    float* out = (float*)d_out;

    char* ws = (char*)d_ws;
    unsigned short* WhT = (unsigned short*)ws;                 // 4 MiB
    float* s1 = (float*)(ws + (4u << 20));                     // 32 KiB
    float* s2 = (float*)(ws + (4u << 20) + (32u << 10));       // 32 KiB
    unsigned short* WT = (unsigned short*)(ws + (4u << 20) + (64u << 10));   // 128 KiB
    float* v1 = (float*)(ws + (4u << 20) + (192u << 10));      // 1 KiB
    float* v2 = (float*)(ws + (4u << 20) + (193u << 10));      // 1 KiB
    float* dpart = (float*)(ws + (5u << 20));                  // 128 KiB
    float* Npart = (float*)(ws + (8u << 20));                  // 32 MiB
    unsigned char* PM = (unsigned char*)(ws + (40u << 20));    // 8 MiB

    hipLaunchKernelGGL(wt_kernel, dim3(256), dim3(256), 0, stream, W, WT);
    hipLaunchKernelGGL(wv_kernel, dim3(256), dim3(256), 0, stream, W, a, v1, v2);
    hipLaunchKernelGGL(pack_kernel, dim3(NNODES), dim3(256), 0, stream, adj, PM);
    hipLaunchKernelGGL(wh_kernel, dim3(128), dim3(256), 0, stream, h, WT, v1, v2, WhT, s1, s2);
    hipLaunchKernelGGL(attn_partial, dim3(512 * NJC), dim3(256), 0, stream,
                       PM, WhT, s1, s2, Npart, dpart);
    hipLaunchKernelGGL(reduce_kernel, dim3(NNODES), dim3(256), 0, stream, Npart, dpart, out);
}

// Round 8
// 459.059 us; speedup vs baseline: 1.3953x; 1.3953x over previous
//
#include <hip/hip_runtime.h>

typedef short s8v  __attribute__((ext_vector_type(8)));
typedef float f4v  __attribute__((ext_vector_type(4)));
typedef int   v4i  __attribute__((ext_vector_type(4)));
typedef float v4f  __attribute__((ext_vector_type(4)));

#define NNODES 8192
#define FDIM   256
#define NJC    4          // j-chunks (split-K factor)
#define JLEN   2048       // columns-j per chunk
#define TROWS  32         // rows per block
#define KSTEP  64         // k per step
#define NSTEP  32         // JLEN / KSTEP

__device__ __forceinline__ float bf2f(unsigned short u) {
    unsigned int x = ((unsigned int)u) << 16;
    return __builtin_bit_cast(float, x);
}
__device__ __forceinline__ unsigned short f2bf(float f) {
    unsigned int x = __builtin_bit_cast(unsigned int, f);
    x += 0x7fffu + ((x >> 16) & 1u);
    return (unsigned short)(x >> 16);
}

// ---------------- Kernel 0: WT[n][k] = bf16(W[k][n]) ----------------
__global__ __launch_bounds__(256) void wt_kernel(const float* __restrict__ W,
                                                 unsigned short* __restrict__ WT) {
    int idx = blockIdx.x * 256 + threadIdx.x;
    int r = idx >> 8, c = idx & 255;
    WT[c * 256 + r] = f2bf(W[r * 256 + c]);
}

// ---------------- Kernel 0b: v1 = W @ a[:256], v2 = W @ a[256:] ----------------
__global__ __launch_bounds__(256) void wv_kernel(const float* __restrict__ W,
                                                 const float* __restrict__ a,
                                                 float* __restrict__ v1, float* __restrict__ v2) {
    __shared__ float r1[256], r2[256];
    int b = blockIdx.x, n = threadIdx.x;
    float w = W[(size_t)b * FDIM + n];
    r1[n] = w * a[n];
    r2[n] = w * a[FDIM + n];
    __syncthreads();
    for (int off = 128; off > 0; off >>= 1) {
        if (n < off) { r1[n] += r1[n + off]; r2[n] += r2[n + off]; }
        __syncthreads();
    }
    if (n == 0) { v1[b] = r1[0]; v2[b] = r2[0]; }
}

// ---------------- Kernel 1: PB = tiled bf16 Wh; s1/s2 = h@v (fp32) ----------------
// PB layout (R7 post-mortem fix — B-frag loads were 64 lines/inst): for
// k-block kb (32 rows of Wh) and n-block t (16 cols), a 1 KiB tile:
//   PB[(kb*16+t)*512 + l15*32 + q*8 + jj] = Wh[kb*32 + q*8 + jj][t*16 + l15]
// so one wave's MFMA B-frag = one contiguous aligned 1 KiB = 16 lines (min).
__global__ __launch_bounds__(256) void wh_kernel(
    const float* __restrict__ h, const unsigned short* __restrict__ WT,
    const float* __restrict__ v1, const float* __restrict__ v2,
    unsigned short* __restrict__ PB,
    float* __restrict__ s1, float* __restrict__ s2)
{
    __shared__ float v1_lds[FDIM], v2_lds[FDIM];
    int tid = threadIdx.x;
    v1_lds[tid] = v1[tid];
    v2_lds[tid] = v2[tid];
    __syncthreads();

    int w = tid >> 6, lane = tid & 63, q = lane >> 4, l15 = lane & 15;
    int i_base = blockIdx.x * 64 + w * 16;

    f4v acc[16] = {};
    float s1p = 0.f, s2p = 0.f;

    for (int k0 = 0; k0 < 256; k0 += 32) {
        const float* hp = h + (size_t)(i_base + l15) * FDIM + k0 + q * 8;
        f4v h0 = *(const f4v*)hp;
        f4v h1 = *(const f4v*)(hp + 4);
        s8v af;
#pragma unroll
        for (int j = 0; j < 4; ++j) {
            af[j]     = (short)f2bf(h0[j]);
            af[4 + j] = (short)f2bf(h1[j]);
            s1p += h0[j] * v1_lds[k0 + q * 8 + j] + h1[j] * v1_lds[k0 + q * 8 + 4 + j];
            s2p += h0[j] * v2_lds[k0 + q * 8 + j] + h1[j] * v2_lds[k0 + q * 8 + 4 + j];
        }
#pragma unroll
        for (int t = 0; t < 16; ++t) {
            s8v bf = *(const s8v*)(WT + (size_t)(t * 16 + l15) * FDIM + k0 + q * 8);
            acc[t] = __builtin_amdgcn_mfma_f32_16x16x32_bf16(af, bf, acc[t], 0, 0, 0);
        }
    }

    s1p += __shfl_xor(s1p, 16, 64);
    s1p += __shfl_xor(s1p, 32, 64);
    s2p += __shfl_xor(s2p, 16, 64);
    s2p += __shfl_xor(s2p, 32, 64);
    if (lane < 16) {
        s1[i_base + lane] = s1p;
        s2[i_base + lane] = s2p;
    }

    // store into tiled PB: i = row, n = t*16 + l15
#pragma unroll
    for (int t = 0; t < 16; ++t)
#pragma unroll
        for (int r = 0; r < 4; ++r) {
            int i = i_base + q * 4 + r;
            size_t a16 = (size_t)((i >> 5) * 16 + t) * 512
                       + l15 * 32 + ((i >> 3) & 3) * 8 + (i & 7);
            PB[a16] = f2bf(acc[t][r]);
        }
}

// ---------------- Kernel 2: split-K partial attention ----------------
// grid 1024 = 256 row-tiles x 4 j-chunks, 256 threads. Block: 32 rows x 256
// cols over j in [jc*2048,(jc+1)*2048), 32 steps of k=64. B-frags from PB
// (contiguous 1 KiB per wave-load); adj inline (proven cheap in R7).
__global__ __launch_bounds__(256) void attn_partial(
    const int* __restrict__ adj, const unsigned short* __restrict__ PB,
    const float* __restrict__ s1, const float* __restrict__ s2,
    float* __restrict__ Npart, float* __restrict__ dpart)
{
    __shared__ float s2_lds[JLEN];                      // 8 KB
    __shared__ unsigned short P_lds[2][TROWS * KSTEP];  // 2 x 4 KB
    __shared__ float dsum_lds[TROWS][8];

    int tid = threadIdx.x;
    int rt = blockIdx.x & 255, jc = blockIdx.x >> 8;
    int j0 = jc * JLEN;

    for (int i = tid; i < JLEN / 4; i += 256)
        ((v4f*)s2_lds)[i] = ((const v4f*)(s2 + j0))[i];

    // P-generator role: (row m 0..31, k-slice idx 0..7), 8 j's per thread/step
    int m = tid >> 3, idx = tid & 7;
    int row_g = rt * TROWS + m;
    float s1v = s1[row_g];
    const int* arow = adj + (size_t)row_g * NNODES + j0 + idx * 8;
    // P write: slot = idx*32+m; XOR idx*16 elems (=8 words) spreads the 8
    // same-slot%8 writers across bank groups
    int woff = ((idx * 32 + m) * 8) ^ (idx * 16);

    // MFMA role: wave g -> cols g*64 + t*16 + l15
    int g = tid >> 6, lane = tid & 63, q = lane >> 4, l15 = lane & 15;
    const unsigned short* pbb = PB + (size_t)(jc * 64) * 16 * 512 + l15 * 32 + q * 8;

    f4v acc[2][4] = {};
    float dsum = 0.0f;

    __syncthreads();  // s2 staged (R5 race fix)

    // prologue: adj(step0) -> P0; adj(step1) parked in cur
    v4i a0 = __builtin_nontemporal_load((const v4i*)(arow));
    v4i a1 = __builtin_nontemporal_load((const v4i*)(arow + 4));
    v4i cur0 = __builtin_nontemporal_load((const v4i*)(arow + KSTEP));
    v4i cur1 = __builtin_nontemporal_load((const v4i*)(arow + KSTEP + 4));
    {
        int kb = idx * 8;
        v4f sA = *(const v4f*)&s2_lds[kb];
        v4f sB = *(const v4f*)&s2_lds[kb + 4];
        s8v pv;
#pragma unroll
        for (int j = 0; j < 4; ++j) {
            float x = s1v + sA[j];
            float p = (a0[j] > 0) ? __expf(fmaxf(x, 0.2f * x)) : 0.0f;
            unsigned short pb = f2bf(p);
            pv[j] = (short)pb; dsum += bf2f(pb);
            float x2 = s1v + sB[j];
            float p2 = (a1[j] > 0) ? __expf(fmaxf(x2, 0.2f * x2)) : 0.0f;
            unsigned short pb2 = f2bf(p2);
            pv[4 + j] = (short)pb2; dsum += bf2f(pb2);
        }
        *(s8v*)&P_lds[0][woff] = pv;
    }
    __syncthreads();

    for (int s = 0; s < NSTEP; ++s) {
        // adj for step s+2
        int kn = (s < NSTEP - 2) ? (s + 2) * KSTEP : 0;
        v4i nx0 = __builtin_nontemporal_load((const v4i*)(arow + kn));
        v4i nx1 = __builtin_nontemporal_load((const v4i*)(arow + kn + 4));

        // B-frags for step s: contiguous 1 KiB per wave-load
        s8v bf[2][4];
#pragma unroll
        for (int c = 0; c < 2; ++c)
#pragma unroll
            for (int t = 0; t < 4; ++t)
                bf[c][t] = *(const s8v*)(pbb + (size_t)((s * 2 + c) * 16 + g * 4 + t) * 512);

        // P for step s+1 from cur
        if (s < NSTEP - 1) {
            int kb = (s + 1) * KSTEP + idx * 8;
            v4f sA = *(const v4f*)&s2_lds[kb];
            v4f sB = *(const v4f*)&s2_lds[kb + 4];
            s8v pv;
#pragma unroll
            for (int j = 0; j < 4; ++j) {
                float x = s1v + sA[j];
                float p = (cur0[j] > 0) ? __expf(fmaxf(x, 0.2f * x)) : 0.0f;
                unsigned short pb = f2bf(p);
                pv[j] = (short)pb; dsum += bf2f(pb);
                float x2 = s1v + sB[j];
                float p2 = (cur1[j] > 0) ? __expf(fmaxf(x2, 0.2f * x2)) : 0.0f;
                unsigned short pb2 = f2bf(p2);
                pv[4 + j] = (short)pb2; dsum += bf2f(pb2);
            }
            *(s8v*)&P_lds[(s + 1) & 1][woff] = pv;
        }

        // A-frags: slice ks = c*4+q, row = h*16+l15; same XOR as writer
        const unsigned short* pbuf = P_lds[s & 1];
        s8v af[2][2];
#pragma unroll
        for (int h = 0; h < 2; ++h)
#pragma unroll
            for (int c = 0; c < 2; ++c) {
                int ks = c * 4 + q;
                af[h][c] = *(const s8v*)&pbuf[((ks * 32 + h * 16 + l15) * 8) ^ (ks * 16)];
            }

#pragma unroll
        for (int h = 0; h < 2; ++h)
#pragma unroll
            for (int c = 0; c < 2; ++c)
#pragma unroll
                for (int t = 0; t < 4; ++t)
                    acc[h][t] = __builtin_amdgcn_mfma_f32_16x16x32_bf16(
                        af[h][c], bf[c][t], acc[h][t], 0, 0, 0);

        __syncthreads();
        cur0 = nx0; cur1 = nx1;
    }

    // partial denominator
    dsum_lds[m][idx] = dsum;
    __syncthreads();
    if (tid < TROWS) {
        float d = 0.f;
#pragma unroll
        for (int j = 0; j < 8; ++j) d += dsum_lds[tid][j];
        dpart[jc * NNODES + rt * TROWS + tid] = d;
    }

    // partial numerator: row = h*16 + q*4 + r, col = g*64 + t*16 + l15
#pragma unroll
    for (int h = 0; h < 2; ++h)
#pragma unroll
        for (int r = 0; r < 4; ++r) {
            int row = h * 16 + q * 4 + r;
            float* base = Npart + ((size_t)(jc * NNODES) + rt * TROWS + row) * FDIM;
#pragma unroll
            for (int t = 0; t < 4; ++t)
                __builtin_nontemporal_store(acc[h][t][r], base + g * 64 + t * 16 + l15);
        }
}

// ---------------- Kernel 3: reduce partials, normalize ----------------
__global__ __launch_bounds__(256) void reduce_kernel(
    const float* __restrict__ Npart, const float* __restrict__ dpart,
    float* __restrict__ out)
{
    int i = blockIdx.x, n = threadIdx.x;
    float d = 0.f, acc = 0.f;
#pragma unroll
    for (int jc = 0; jc < NJC; ++jc) {
        d += dpart[jc * NNODES + i];
        acc += Npart[((size_t)(jc * NNODES) + i) * FDIM + n];
    }
    out[(size_t)i * FDIM + n] = acc / fmaxf(d, 1e-30f);
}

extern "C" void kernel_launch(void* const* d_in, const int* in_sizes, int n_in,
                              void* d_out, int out_size, void* d_ws, size_t ws_size,
                              hipStream_t stream) {
    const float* h   = (const float*)d_in[0];
    const int*   adj = (const int*)d_in[1];
    const float* W   = (const float*)d_in[2];
    const float* a   = (const float*)d_in[3];
    float* out = (float*)d_out;

    char* ws = (char*)d_ws;
    unsigned short* PB = (unsigned short*)ws;                  // 4 MiB (tiled Wh)
    float* s1 = (float*)(ws + (4u << 20));                     // 32 KiB
    float* s2 = (float*)(ws + (4u << 20) + (32u << 10));       // 32 KiB
    unsigned short* WT = (unsigned short*)(ws + (4u << 20) + (64u << 10));   // 128 KiB
    float* v1 = (float*)(ws + (4u << 20) + (192u << 10));      // 1 KiB
    float* v2 = (float*)(ws + (4u << 20) + (193u << 10));      // 1 KiB
    float* dpart = (float*)(ws + (5u << 20));                  // 128 KiB
    float* Npart = (float*)(ws + (8u << 20));                  // 32 MiB

    hipLaunchKernelGGL(wt_kernel, dim3(256), dim3(256), 0, stream, W, WT);
    hipLaunchKernelGGL(wv_kernel, dim3(256), dim3(256), 0, stream, W, a, v1, v2);
    hipLaunchKernelGGL(wh_kernel, dim3(128), dim3(256), 0, stream, h, WT, v1, v2, PB, s1, s2);
    hipLaunchKernelGGL(attn_partial, dim3(256 * NJC), dim3(256), 0, stream,
                       adj, PB, s1, s2, Npart, dpart);
    hipLaunchKernelGGL(reduce_kernel, dim3(NNODES), dim3(256), 0, stream, Npart, dpart, out);
}

// Round 9
// 444.308 us; speedup vs baseline: 1.4416x; 1.0332x over previous
//
#include <hip/hip_runtime.h>

typedef short s8v  __attribute__((ext_vector_type(8)));
typedef float f4v  __attribute__((ext_vector_type(4)));
typedef int   v4i  __attribute__((ext_vector_type(4)));
typedef float v4f  __attribute__((ext_vector_type(4)));

#define NNODES 8192
#define FDIM   256
#define NJC    4          // j-chunks (split-K factor)
#define JLEN   2048       // columns-j per chunk
#define TROWS  64         // rows per block (R9: 32->64, B-frag reg reuse x4)
#define KSTEP  32         // k per step = one PB k-tile
#define NSTEP  64         // JLEN / KSTEP

__device__ __forceinline__ float bf2f(unsigned short u) {
    unsigned int x = ((unsigned int)u) << 16;
    return __builtin_bit_cast(float, x);
}
__device__ __forceinline__ unsigned short f2bf(float f) {
    unsigned int x = __builtin_bit_cast(unsigned int, f);
    x += 0x7fffu + ((x >> 16) & 1u);
    return (unsigned short)(x >> 16);
}

// ---------------- Kernel 0: WT[n][k] = bf16(W[k][n]) ----------------
__global__ __launch_bounds__(256) void wt_kernel(const float* __restrict__ W,
                                                 unsigned short* __restrict__ WT) {
    int idx = blockIdx.x * 256 + threadIdx.x;
    int r = idx >> 8, c = idx & 255;
    WT[c * 256 + r] = f2bf(W[r * 256 + c]);
}

// ---------------- Kernel 0b: v1 = W @ a[:256], v2 = W @ a[256:] ----------------
__global__ __launch_bounds__(256) void wv_kernel(const float* __restrict__ W,
                                                 const float* __restrict__ a,
                                                 float* __restrict__ v1, float* __restrict__ v2) {
    __shared__ float r1[256], r2[256];
    int b = blockIdx.x, n = threadIdx.x;
    float w = W[(size_t)b * FDIM + n];
    r1[n] = w * a[n];
    r2[n] = w * a[FDIM + n];
    __syncthreads();
    for (int off = 128; off > 0; off >>= 1) {
        if (n < off) { r1[n] += r1[n + off]; r2[n] += r2[n + off]; }
        __syncthreads();
    }
    if (n == 0) { v1[b] = r1[0]; v2[b] = r2[0]; }
}

// ---------------- Kernel 1: PB = tiled bf16 Wh; s1/s2 = h@v (fp32) ----------------
// PB: for k-block kb (32 Wh-rows) and n-block t (16 cols), 1 KiB tile:
//   PB[(kb*16+t)*512 + l15*32 + q*8 + jj] = Wh[kb*32 + q*8 + jj][t*16 + l15]
// -> one wave's MFMA B-frag = one contiguous aligned 1 KiB = 16 lines (min).
__global__ __launch_bounds__(256) void wh_kernel(
    const float* __restrict__ h, const unsigned short* __restrict__ WT,
    const float* __restrict__ v1, const float* __restrict__ v2,
    unsigned short* __restrict__ PB,
    float* __restrict__ s1, float* __restrict__ s2)
{
    __shared__ float v1_lds[FDIM], v2_lds[FDIM];
    int tid = threadIdx.x;
    v1_lds[tid] = v1[tid];
    v2_lds[tid] = v2[tid];
    __syncthreads();

    int w = tid >> 6, lane = tid & 63, q = lane >> 4, l15 = lane & 15;
    int i_base = blockIdx.x * 64 + w * 16;

    f4v acc[16] = {};
    float s1p = 0.f, s2p = 0.f;

    for (int k0 = 0; k0 < 256; k0 += 32) {
        const float* hp = h + (size_t)(i_base + l15) * FDIM + k0 + q * 8;
        f4v h0 = *(const f4v*)hp;
        f4v h1 = *(const f4v*)(hp + 4);
        s8v af;
#pragma unroll
        for (int j = 0; j < 4; ++j) {
            af[j]     = (short)f2bf(h0[j]);
            af[4 + j] = (short)f2bf(h1[j]);
            s1p += h0[j] * v1_lds[k0 + q * 8 + j] + h1[j] * v1_lds[k0 + q * 8 + 4 + j];
            s2p += h0[j] * v2_lds[k0 + q * 8 + j] + h1[j] * v2_lds[k0 + q * 8 + 4 + j];
        }
#pragma unroll
        for (int t = 0; t < 16; ++t) {
            s8v bf = *(const s8v*)(WT + (size_t)(t * 16 + l15) * FDIM + k0 + q * 8);
            acc[t] = __builtin_amdgcn_mfma_f32_16x16x32_bf16(af, bf, acc[t], 0, 0, 0);
        }
    }

    s1p += __shfl_xor(s1p, 16, 64);
    s1p += __shfl_xor(s1p, 32, 64);
    s2p += __shfl_xor(s2p, 16, 64);
    s2p += __shfl_xor(s2p, 32, 64);
    if (lane < 16) {
        s1[i_base + lane] = s1p;
        s2[i_base + lane] = s2p;
    }

#pragma unroll
    for (int t = 0; t < 16; ++t)
#pragma unroll
        for (int r = 0; r < 4; ++r) {
            int i = i_base + q * 4 + r;
            size_t a16 = (size_t)((i >> 5) * 16 + t) * 512
                       + l15 * 32 + ((i >> 3) & 3) * 8 + (i & 7);
            PB[a16] = f2bf(acc[t][r]);
        }
}

// ---------------- Kernel 2: split-K partial attention ----------------
// grid 512 = 128 row-tiles x 4 j-chunks, 256 threads. Block: 64 rows x 256
// cols, 64 steps of k=32. Each wave holds 4 rowhalves (acc[4][4]) so B-frags
// are loaded ONCE per block -> L2 B-traffic 1 GiB -> 512 MiB (R8 post-mortem:
// L2 at 56 B/cyc/CU was the largest term).
__global__ __launch_bounds__(256, 3) void attn_partial(
    const int* __restrict__ adj, const unsigned short* __restrict__ PB,
    const float* __restrict__ s1, const float* __restrict__ s2,
    float* __restrict__ Npart, float* __restrict__ dpart)
{
    __shared__ float s2_lds[JLEN];                      // 8 KB
    __shared__ unsigned short P_lds[2][TROWS * KSTEP];  // 2 x 4 KB
    __shared__ float dsum_lds[TROWS][4];

    int tid = threadIdx.x;
    int rt = blockIdx.x & 127, jc = blockIdx.x >> 7;
    int j0 = jc * JLEN;

    for (int i = tid; i < JLEN / 4; i += 256)
        ((v4f*)s2_lds)[i] = ((const v4f*)(s2 + j0))[i];

    // P-generator role: (row m 0..63, k-slice idx 0..3), 8 j's per thread/step
    int m = tid >> 2, idx = tid & 3;
    int row_g = rt * TROWS + m;
    float s1v = s1[row_g];
    const int* arow = adj + (size_t)row_g * NNODES + j0 + idx * 8;
    // write slot = idx*64+m, elem addr ^ idx*16 (matches reader swizzle)
    int woff = ((idx * 64 + m) * 8) ^ (idx * 16);

    // MFMA role: wave g -> cols g*64 + t*16 + l15; rowhalves rh=0..3 in-register
    int g = tid >> 6, lane = tid & 63, q = lane >> 4, l15 = lane & 15;
    const unsigned short* pbb = PB + (size_t)(jc * 64) * 16 * 512 + l15 * 32 + q * 8;

    f4v acc[4][4] = {};
    float dsum = 0.0f;

    __syncthreads();  // s2 staged (R5 race fix)

    // prologue: adj(step0) -> P0; adj(step1) parked in cur
    v4i a0 = __builtin_nontemporal_load((const v4i*)(arow));
    v4i a1 = __builtin_nontemporal_load((const v4i*)(arow + 4));
    v4i cur0 = __builtin_nontemporal_load((const v4i*)(arow + KSTEP));
    v4i cur1 = __builtin_nontemporal_load((const v4i*)(arow + KSTEP + 4));
    {
        int kb = idx * 8;
        v4f sA = *(const v4f*)&s2_lds[kb];
        v4f sB = *(const v4f*)&s2_lds[kb + 4];
        s8v pv;
#pragma unroll
        for (int j = 0; j < 4; ++j) {
            float x = s1v + sA[j];
            float p = (a0[j] > 0) ? __expf(fmaxf(x, 0.2f * x)) : 0.0f;
            unsigned short pb = f2bf(p);
            pv[j] = (short)pb; dsum += bf2f(pb);
            float x2 = s1v + sB[j];
            float p2 = (a1[j] > 0) ? __expf(fmaxf(x2, 0.2f * x2)) : 0.0f;
            unsigned short pb2 = f2bf(p2);
            pv[4 + j] = (short)pb2; dsum += bf2f(pb2);
        }
        *(s8v*)&P_lds[0][woff] = pv;
    }
    __syncthreads();

    for (int s = 0; s < NSTEP; ++s) {
        // adj for step s+2
        int kn = (s < NSTEP - 2) ? (s + 2) * KSTEP : 0;
        v4i nx0 = __builtin_nontemporal_load((const v4i*)(arow + kn));
        v4i nx1 = __builtin_nontemporal_load((const v4i*)(arow + kn + 4));

        // B-frags for step s: one k-tile (kb = jc*64+s), cols g*64..g*64+63;
        // contiguous 1 KiB per wave-load, loaded ONCE, reused over 4 rowhalves
        s8v bf[4];
#pragma unroll
        for (int t = 0; t < 4; ++t)
            bf[t] = *(const s8v*)(pbb + (size_t)(s * 16 + g * 4 + t) * 512);

        // P for step s+1 from cur
        if (s < NSTEP - 1) {
            int kb = (s + 1) * KSTEP + idx * 8;
            v4f sA = *(const v4f*)&s2_lds[kb];
            v4f sB = *(const v4f*)&s2_lds[kb + 4];
            s8v pv;
#pragma unroll
            for (int j = 0; j < 4; ++j) {
                float x = s1v + sA[j];
                float p = (cur0[j] > 0) ? __expf(fmaxf(x, 0.2f * x)) : 0.0f;
                unsigned short pb = f2bf(p);
                pv[j] = (short)pb; dsum += bf2f(pb);
                float x2 = s1v + sB[j];
                float p2 = (cur1[j] > 0) ? __expf(fmaxf(x2, 0.2f * x2)) : 0.0f;
                unsigned short pb2 = f2bf(p2);
                pv[4 + j] = (short)pb2; dsum += bf2f(pb2);
            }
            *(s8v*)&P_lds[(s + 1) & 1][woff] = pv;
        }

        // MFMA over 4 rowhalves; A-frag loaded per-rh to cap register pressure
        const unsigned short* pbuf = P_lds[s & 1];
#pragma unroll
        for (int rh = 0; rh < 4; ++rh) {
            s8v af = *(const s8v*)&pbuf[((q * 64 + rh * 16 + l15) * 8) ^ (q * 16)];
#pragma unroll
            for (int t = 0; t < 4; ++t)
                acc[rh][t] = __builtin_amdgcn_mfma_f32_16x16x32_bf16(af, bf[t], acc[rh][t], 0, 0, 0);
        }

        __syncthreads();
        cur0 = nx0; cur1 = nx1;
    }

    // partial denominator
    dsum_lds[m][idx] = dsum;
    __syncthreads();
    if (tid < TROWS) {
        float d = dsum_lds[tid][0] + dsum_lds[tid][1] + dsum_lds[tid][2] + dsum_lds[tid][3];
        dpart[jc * NNODES + rt * TROWS + tid] = d;
    }

    // partial numerator: row = rh*16 + q*4 + r, col = g*64 + t*16 + l15
#pragma unroll
    for (int rh = 0; rh < 4; ++rh)
#pragma unroll
        for (int r = 0; r < 4; ++r) {
            int row = rh * 16 + q * 4 + r;
            float* base = Npart + ((size_t)(jc * NNODES) + rt * TROWS + row) * FDIM;
#pragma unroll
            for (int t = 0; t < 4; ++t)
                __builtin_nontemporal_store(acc[rh][t][r], base + g * 64 + t * 16 + l15);
        }
}

// ---------------- Kernel 3: reduce partials, normalize ----------------
__global__ __launch_bounds__(256) void reduce_kernel(
    const float* __restrict__ Npart, const float* __restrict__ dpart,
    float* __restrict__ out)
{
    int i = blockIdx.x, n = threadIdx.x;
    float d = 0.f, acc = 0.f;
#pragma unroll
    for (int jc = 0; jc < NJC; ++jc) {
        d += dpart[jc * NNODES + i];
        acc += Npart[((size_t)(jc * NNODES) + i) * FDIM + n];
    }
    out[(size_t)i * FDIM + n] = acc / fmaxf(d, 1e-30f);
}

extern "C" void kernel_launch(void* const* d_in, const int* in_sizes, int n_in,
                              void* d_out, int out_size, void* d_ws, size_t ws_size,
                              hipStream_t stream) {
    const float* h   = (const float*)d_in[0];
    const int*   adj = (const int*)d_in[1];
    const float* W   = (const float*)d_in[2];
    const float* a   = (const float*)d_in[3];
    float* out = (float*)d_out;

    char* ws = (char*)d_ws;
    unsigned short* PB = (unsigned short*)ws;                  // 4 MiB (tiled Wh)
    float* s1 = (float*)(ws + (4u << 20));                     // 32 KiB
    float* s2 = (float*)(ws + (4u << 20) + (32u << 10));       // 32 KiB
    unsigned short* WT = (unsigned short*)(ws + (4u << 20) + (64u << 10));   // 128 KiB
    float* v1 = (float*)(ws + (4u << 20) + (192u << 10));      // 1 KiB
    float* v2 = (float*)(ws + (4u << 20) + (193u << 10));      // 1 KiB
    float* dpart = (float*)(ws + (5u << 20));                  // 128 KiB
    float* Npart = (float*)(ws + (8u << 20));                  // 32 MiB

    hipLaunchKernelGGL(wt_kernel, dim3(256), dim3(256), 0, stream, W, WT);
    hipLaunchKernelGGL(wv_kernel, dim3(256), dim3(256), 0, stream, W, a, v1, v2);
    hipLaunchKernelGGL(wh_kernel, dim3(128), dim3(256), 0, stream, h, WT, v1, v2, PB, s1, s2);
    hipLaunchKernelGGL(attn_partial, dim3(128 * NJC), dim3(256), 0, stream,
                       adj, PB, s1, s2, Npart, dpart);
    hipLaunchKernelGGL(reduce_kernel, dim3(NNODES), dim3(256), 0, stream, Npart, dpart, out);
}